// Round 1
// baseline (743.413 us; speedup 1.0000x reference)
//
#include <hip/hip_runtime.h>
#include <hip/hip_fp16.h>
#include <stdint.h>

#define HD   4096
#define MDIM 14336
#define TOKN 64
#define KSPLIT 8
#define MCHUNK (MDIM / KSPLIT)   /* 1792 */
#define KB_DOWN (MCHUNK / 64)    /* 28 */

typedef _Float16 half8 __attribute__((ext_vector_type(8)));
typedef float    f32x4 __attribute__((ext_vector_type(4)));

__constant__ float NF4_TBL[16] = {
    -1.0f, -0.6961928009986877f, -0.5250730514526367f, -0.39491748809814453f,
    -0.28444138169288635f, -0.18477343022823334f, -0.09105003625154495f, 0.0f,
    0.07958029955625534f, 0.16093020141124725f, 0.24611230194568634f,
    0.33791524171829224f, 0.44070982933044434f, 0.5626170039176941f,
    0.8333333134651184f, 1.0f};

// 256-entry pair LUT: idx = c0 | (c1<<4)  ->  packed (half(NF4[c0]), half(NF4[c1]))
__device__ __forceinline__ void lut_init(uint32_t* lut) {
  int t = threadIdx.x;
  if (t < 256) {
    __half lo = __float2half(NF4_TBL[t & 15]);
    __half hi = __float2half(NF4_TBL[t >> 4]);
    lut[t] = (uint32_t)__half_as_ushort(lo) |
             ((uint32_t)__half_as_ushort(hi) << 16);
  }
  __syncthreads();
}

__device__ __forceinline__ half8 mk_bfrag(const uint32_t* lut, int4 ca, int4 cb) {
  union { uint32_t u[4]; half8 h; } bu;
  bu.u[0] = lut[ca.x | (ca.y << 4)];
  bu.u[1] = lut[ca.z | (ca.w << 4)];
  bu.u[2] = lut[cb.x | (cb.y << 4)];
  bu.u[3] = lut[cb.z | (cb.w << 4)];
  return bu.h;
}

// One wave computes a 64(token) x 16(col) output strip, reducing over nkb*64 k.
// crow: codes row base (already + row*K + ksplit offset), per-lane row = base col + (lane&15)
// srow: per-row scale ptr, stride 1 per 64-block
// arow: fp16 activations, pre-offset by (lane&15)*astride + q*8; astr16 = 16*astride
// kl = (lane>>4)*8
__device__ __forceinline__ void nf4_gemm_k(
    const int* __restrict__ crow, const float* __restrict__ srow,
    const _Float16* __restrict__ arow, int astr16, int nkb,
    const uint32_t* lut, int kl, f32x4 acc[4])
{
  const int ktot = nkb * 64;
  int4 ca = *(const int4*)(crow + kl);
  int4 cb = *(const int4*)(crow + kl + 4);
  for (int kb = 0; kb < nkb; ++kb) {
    _Float16 sh = (_Float16)srow[kb];
    half8 sv = {sh, sh, sh, sh, sh, sh, sh, sh};
#pragma unroll
    for (int kk = 0; kk < 2; ++kk) {
      int klin  = kb * 64 + kk * 32;
      int knext = klin + 32;
      knext = (knext < ktot) ? knext : 0;            // wrap: harmless prefetch
      int4 na = *(const int4*)(crow + knext + kl);
      int4 nb = *(const int4*)(crow + knext + kl + 4);
      half8 bf = mk_bfrag(lut, ca, cb) * sv;         // scale folded in fp16
#pragma unroll
      for (int t = 0; t < 4; ++t) {
        half8 af = *(const half8*)(arow + (size_t)t * astr16 + klin);
        acc[t] = __builtin_amdgcn_mfma_f32_16x16x32_f16(af, bf, acc[t], 0, 0, 0);
      }
      ca = na; cb = nb;
    }
  }
}

// x fp32 -> fp16
__global__ void k_cvt_x(const float* __restrict__ x, _Float16* __restrict__ xh) {
  int i = blockIdx.x * blockDim.x + threadIdx.x;
  float4 v = ((const float4*)x)[i];
  union { _Float16 h[4]; uint2 u; } o;
  o.h[0] = (_Float16)v.x; o.h[1] = (_Float16)v.y;
  o.h[2] = (_Float16)v.z; o.h[3] = (_Float16)v.w;
  ((uint2*)xh)[i] = o.u;
}

// gate & up GEMM fused in one launch: blocks [0,224) -> gate, [224,448) -> up
__global__ __launch_bounds__(256, 2) void k_gemm_gu(
    const int* __restrict__ gc, const float* __restrict__ gs,
    const int* __restrict__ uc, const float* __restrict__ us,
    const _Float16* __restrict__ xh,
    float* __restrict__ gout, float* __restrict__ uout)
{
  __shared__ uint32_t lut[256];
  lut_init(lut);
  int bx = blockIdx.x;
  int mat = (bx >= 224);
  int mblk = mat ? bx - 224 : bx;
  const int*   codes = mat ? uc : gc;
  const float* scl   = mat ? us : gs;
  float*       outp  = mat ? uout : gout;

  int tid = threadIdx.x;
  int lane = tid & 63, wid = tid >> 6;
  int r15 = lane & 15, q = lane >> 4;
  int mbase = mblk * 64 + wid * 16;
  int mrow  = mbase + r15;

  const int*      crow = codes + (size_t)mrow * HD;
  const float*    srow = scl + (size_t)mrow * 64;
  const _Float16* arow = xh + (size_t)r15 * HD + q * 8;

  f32x4 acc[4];
#pragma unroll
  for (int t = 0; t < 4; ++t) acc[t] = (f32x4){0.f, 0.f, 0.f, 0.f};

  nf4_gemm_k(crow, srow, arow, 16 * HD, HD / 64, lut, q * 8, acc);

#pragma unroll
  for (int t = 0; t < 4; ++t)
#pragma unroll
    for (int r = 0; r < 4; ++r) {
      int token = t * 16 + 4 * q + r;              // D: row = 4*(lane>>4)+reg
      outp[(size_t)token * MDIM + mbase + r15] = acc[t][r];
    }
}

// h = silu(g)*u, fp32 -> fp16
__global__ void k_swiglu(const float* __restrict__ g, const float* __restrict__ u,
                         _Float16* __restrict__ h) {
  int i = blockIdx.x * blockDim.x + threadIdx.x;
  float4 gv = ((const float4*)g)[i];
  float4 uv = ((const float4*)u)[i];
  union { _Float16 h4[4]; uint2 w; } o;
  o.h4[0] = (_Float16)(gv.x / (1.f + __expf(-gv.x)) * uv.x);
  o.h4[1] = (_Float16)(gv.y / (1.f + __expf(-gv.y)) * uv.y);
  o.h4[2] = (_Float16)(gv.z / (1.f + __expf(-gv.z)) * uv.z);
  o.h4[3] = (_Float16)(gv.w / (1.f + __expf(-gv.w)) * uv.w);
  ((uint2*)h)[i] = o.w;
}

// down-proj, K-split x8: block = (nblk = bx&63, split = bx>>6)
__global__ __launch_bounds__(256, 2) void k_gemm_down(
    const int* __restrict__ dc, const float* __restrict__ ds,
    const _Float16* __restrict__ h, float* __restrict__ part)
{
  __shared__ uint32_t lut[256];
  lut_init(lut);
  int bx = blockIdx.x;
  int nblk = bx & 63, sp = bx >> 6;
  int tid = threadIdx.x;
  int lane = tid & 63, wid = tid >> 6;
  int r15 = lane & 15, q = lane >> 4;
  int nbase = nblk * 64 + wid * 16;
  int nrow  = nbase + r15;

  const int*      crow = dc + (size_t)nrow * MDIM + sp * MCHUNK;
  const float*    srow = ds + (size_t)nrow * (MDIM / 64) + sp * KB_DOWN;
  const _Float16* arow = h + (size_t)r15 * MDIM + sp * MCHUNK + q * 8;

  f32x4 acc[4];
#pragma unroll
  for (int t = 0; t < 4; ++t) acc[t] = (f32x4){0.f, 0.f, 0.f, 0.f};

  nf4_gemm_k(crow, srow, arow, 16 * MDIM, KB_DOWN, lut, q * 8, acc);

  float* op = part + (size_t)sp * (TOKN * HD);
#pragma unroll
  for (int t = 0; t < 4; ++t)
#pragma unroll
    for (int r = 0; r < 4; ++r) {
      int token = t * 16 + 4 * q + r;
      op[(size_t)token * HD + nbase + r15] = acc[t][r];
    }
}

__global__ void k_reduce(const float* __restrict__ part, float* __restrict__ out) {
  int i = blockIdx.x * blockDim.x + threadIdx.x;
  float4 a = ((const float4*)part)[i];
#pragma unroll
  for (int s = 1; s < KSPLIT; ++s) {
    float4 b = ((const float4*)(part + (size_t)s * (TOKN * HD)))[i];
    a.x += b.x; a.y += b.y; a.z += b.z; a.w += b.w;
  }
  ((float4*)out)[i] = a;
}

extern "C" void kernel_launch(void* const* d_in, const int* in_sizes, int n_in,
                              void* d_out, int out_size, void* d_ws, size_t ws_size,
                              hipStream_t stream) {
  (void)in_sizes; (void)n_in; (void)out_size; (void)ws_size;
  const float* x  = (const float*)d_in[0];
  const int*   gc = (const int*)d_in[1];
  const float* gs = (const float*)d_in[2];
  const int*   uc = (const int*)d_in[3];
  const float* us = (const float*)d_in[4];
  const int*   dc = (const int*)d_in[5];
  const float* ds = (const float*)d_in[6];
  float* out = (float*)d_out;

  char* w = (char*)d_ws;
  const size_t XH_B = (size_t)TOKN * HD * sizeof(_Float16);    // 512 KB
  const size_t H_B  = (size_t)TOKN * MDIM * sizeof(_Float16);  // 1.75 MB
  const size_t G_B  = (size_t)TOKN * MDIM * sizeof(float);     // 3.5 MB
  _Float16* xh   = (_Float16*)w;
  _Float16* hbuf = (_Float16*)(w + XH_B);
  float*    gbuf = (float*)(w + XH_B + H_B);
  float*    ubuf = (float*)(w + XH_B + H_B + G_B);
  float*    part = (float*)(w + XH_B + H_B);   // reuses g/u region (dead by then)

  k_cvt_x   <<<256, 256, 0, stream>>>(x, xh);                       // 64x4096 /4
  k_gemm_gu <<<448, 256, 0, stream>>>(gc, gs, uc, us, xh, gbuf, ubuf);
  k_swiglu  <<<896, 256, 0, stream>>>(gbuf, ubuf, hbuf);            // 64x14336 /4
  k_gemm_down<<<512, 256, 0, stream>>>(dc, ds, hbuf, part);
  k_reduce  <<<256, 256, 0, stream>>>(part, out);
}

// Round 2
// 710.968 us; speedup vs baseline: 1.0456x; 1.0456x over previous
//
#include <hip/hip_runtime.h>
#include <hip/hip_fp16.h>
#include <stdint.h>

#define HD   4096
#define MDIM 14336
#define TOKN 64

typedef _Float16 half8 __attribute__((ext_vector_type(8)));
typedef float    f32x4 __attribute__((ext_vector_type(4)));

__constant__ float NF4_TBL[16] = {
    -1.0f, -0.6961928009986877f, -0.5250730514526367f, -0.39491748809814453f,
    -0.28444138169288635f, -0.18477343022823334f, -0.09105003625154495f, 0.0f,
    0.07958029955625534f, 0.16093020141124725f, 0.24611230194568634f,
    0.33791524171829224f, 0.44070982933044434f, 0.5626170039176941f,
    0.8333333134651184f, 1.0f};

// 256-entry pair LUT: idx = c0 | (c1<<4) -> packed (half(NF4[c0]), half(NF4[c1]))
__device__ __forceinline__ void lut_init(uint32_t* lut) {
  int t = threadIdx.x;
  if (t < 256) {
    __half lo = __float2half(NF4_TBL[t & 15]);
    __half hi = __float2half(NF4_TBL[t >> 4]);
    lut[t] = (uint32_t)__half_as_ushort(lo) |
             ((uint32_t)__half_as_ushort(hi) << 16);
  }
  __syncthreads();
}

__device__ __forceinline__ half8 mk_bfrag(const uint32_t* lut, int4 ca, int4 cb) {
  union { uint32_t u[4]; half8 h; } bu;
  bu.u[0] = lut[ca.x | (ca.y << 4)];
  bu.u[1] = lut[ca.z | (ca.w << 4)];
  bu.u[2] = lut[cb.x | (cb.y << 4)];
  bu.u[3] = lut[cb.z | (cb.w << 4)];
  return bu.h;
}

// Compute one 64-code scale block: 2 B-fragments, 8 MFMAs (4 token tiles x 2 k-halves)
__device__ __forceinline__ void blk_compute(
    const uint32_t* lut, int4 c0, int4 c1, int4 c2, int4 c3, float s,
    const _Float16* __restrict__ arow, int astr16, int klin, f32x4 acc[4])
{
  _Float16 sh = (_Float16)s;
  half8 sv = {sh, sh, sh, sh, sh, sh, sh, sh};
  half8 bf0 = mk_bfrag(lut, c0, c1) * sv;
  half8 bf1 = mk_bfrag(lut, c2, c3) * sv;
#pragma unroll
  for (int t = 0; t < 4; ++t) {
    half8 a0 = *(const half8*)(arow + (size_t)t * astr16 + klin);
    half8 a1 = *(const half8*)(arow + (size_t)t * astr16 + klin + 32);
    acc[t] = __builtin_amdgcn_mfma_f32_16x16x32_f16(a0, bf0, acc[t], 0, 0, 0);
    acc[t] = __builtin_amdgcn_mfma_f32_16x16x32_f16(a1, bf1, acc[t], 0, 0, 0);
  }
}

// 2-stage (A/B) software-pipelined K loop over nkb 64-code blocks (nkb even, >=4).
// Prefetch distance ~1.5 block-computes: 8 code int4-loads + 1 scale in flight.
__device__ __forceinline__ void nf4_gemm_pipe(
    const int* __restrict__ crow, const float* __restrict__ srow,
    const _Float16* __restrict__ arow, int astr16, int nkb,
    const uint32_t* lut, int kl, f32x4 acc[4])
{
  int4 Ac0, Ac1, Ac2, Ac3; float As;
  int4 Bc0, Bc1, Bc2, Bc3; float Bs;
#define LOADST(P, kb)                                        \
  P##c0 = *(const int4*)(crow + (kb) * 64 + kl);             \
  P##c1 = *(const int4*)(crow + (kb) * 64 + kl + 4);         \
  P##c2 = *(const int4*)(crow + (kb) * 64 + 32 + kl);        \
  P##c3 = *(const int4*)(crow + (kb) * 64 + 32 + kl + 4);    \
  P##s  = srow[(kb)];

  LOADST(A, 0)
  LOADST(B, 1)
  int kb = 0;
  for (; kb + 3 < nkb; kb += 2) {
    blk_compute(lut, Ac0, Ac1, Ac2, Ac3, As, arow, astr16, kb * 64, acc);
    LOADST(A, kb + 2)
    blk_compute(lut, Bc0, Bc1, Bc2, Bc3, Bs, arow, astr16, (kb + 1) * 64, acc);
    LOADST(B, kb + 3)
  }
  blk_compute(lut, Ac0, Ac1, Ac2, Ac3, As, arow, astr16, kb * 64, acc);
  blk_compute(lut, Bc0, Bc1, Bc2, Bc3, Bs, arow, astr16, (kb + 1) * 64, acc);
#undef LOADST
}

// x fp32 -> fp16
__global__ void k_cvt_x(const float* __restrict__ x, _Float16* __restrict__ xh) {
  int i = blockIdx.x * blockDim.x + threadIdx.x;
  float4 v = ((const float4*)x)[i];
  union { _Float16 h[4]; uint2 u; } o;
  o.h[0] = (_Float16)v.x; o.h[1] = (_Float16)v.y;
  o.h[2] = (_Float16)v.z; o.h[3] = (_Float16)v.w;
  ((uint2*)xh)[i] = o.u;
}

// gate & up GEMM, K-split: grid = 448*gsplit. bx -> (sp, mat, mblk)
__global__ __launch_bounds__(256, 4) void k_gemm_gu(
    const int* __restrict__ gc, const float* __restrict__ gs,
    const int* __restrict__ uc, const float* __restrict__ us,
    const _Float16* __restrict__ xh,
    float* __restrict__ gpart, float* __restrict__ upart, int gsplit)
{
  __shared__ uint32_t lut[256];
  lut_init(lut);
  int bx = blockIdx.x;
  int sp = bx % gsplit;
  int r  = bx / gsplit;
  int mat  = (r >= 224);
  int mblk = mat ? r - 224 : r;
  const int*   codes = mat ? uc : gc;
  const float* scl   = mat ? us : gs;
  float*       outp  = (mat ? upart : gpart) + (size_t)sp * (TOKN * MDIM);

  int kch = HD / gsplit;       // K chunk per split
  int nkb = kch / 64;

  int tid = threadIdx.x;
  int lane = tid & 63, wid = tid >> 6;
  int r15 = lane & 15, q = lane >> 4;
  int mbase = mblk * 64 + wid * 16;
  int mrow  = mbase + r15;

  const int*      crow = codes + (size_t)mrow * HD + (size_t)sp * kch;
  const float*    srow = scl + (size_t)mrow * (HD / 64) + (size_t)sp * nkb;
  const _Float16* arow = xh + (size_t)r15 * HD + (size_t)sp * kch + q * 8;

  f32x4 acc[4];
#pragma unroll
  for (int t = 0; t < 4; ++t) acc[t] = (f32x4){0.f, 0.f, 0.f, 0.f};

  nf4_gemm_pipe(crow, srow, arow, 16 * HD, nkb, lut, q * 8, acc);

#pragma unroll
  for (int t = 0; t < 4; ++t)
#pragma unroll
    for (int rr = 0; rr < 4; ++rr) {
      int token = t * 16 + 4 * q + rr;          // D: row = 4*(lane>>4)+reg
      outp[(size_t)token * MDIM + mbase + r15] = acc[t][rr];
    }
}

// fused split-reduce + SwiGLU, fp32 parts -> fp16 h
__global__ void k_reduce_swiglu(const float* __restrict__ gpart,
                                const float* __restrict__ upart,
                                _Float16* __restrict__ h, int gsplit) {
  int i = blockIdx.x * blockDim.x + threadIdx.x;
  float4 g = ((const float4*)gpart)[i];
  float4 u = ((const float4*)upart)[i];
  for (int s = 1; s < gsplit; ++s) {
    float4 gb = ((const float4*)(gpart + (size_t)s * (TOKN * MDIM)))[i];
    float4 ub = ((const float4*)(upart + (size_t)s * (TOKN * MDIM)))[i];
    g.x += gb.x; g.y += gb.y; g.z += gb.z; g.w += gb.w;
    u.x += ub.x; u.y += ub.y; u.z += ub.z; u.w += ub.w;
  }
  union { _Float16 h4[4]; uint2 w; } o;
  o.h4[0] = (_Float16)(g.x / (1.f + __expf(-g.x)) * u.x);
  o.h4[1] = (_Float16)(g.y / (1.f + __expf(-g.y)) * u.y);
  o.h4[2] = (_Float16)(g.z / (1.f + __expf(-g.z)) * u.z);
  o.h4[3] = (_Float16)(g.w / (1.f + __expf(-g.w)) * u.w);
  ((uint2*)h)[i] = o.w;
}

// down-proj GEMM, K-split: grid = 64*dsplit. bx -> (sp, nblk)
__global__ __launch_bounds__(256, 4) void k_gemm_down(
    const int* __restrict__ dc, const float* __restrict__ ds,
    const _Float16* __restrict__ h, float* __restrict__ part, int dsplit)
{
  __shared__ uint32_t lut[256];
  lut_init(lut);
  int bx = blockIdx.x;
  int sp   = bx % dsplit;
  int nblk = bx / dsplit;

  int kch = MDIM / dsplit;
  int nkb = kch / 64;

  int tid = threadIdx.x;
  int lane = tid & 63, wid = tid >> 6;
  int r15 = lane & 15, q = lane >> 4;
  int nbase = nblk * 64 + wid * 16;
  int nrow  = nbase + r15;

  const int*      crow = dc + (size_t)nrow * MDIM + (size_t)sp * kch;
  const float*    srow = ds + (size_t)nrow * (MDIM / 64) + (size_t)sp * nkb;
  const _Float16* arow = h + (size_t)r15 * MDIM + (size_t)sp * kch + q * 8;

  f32x4 acc[4];
#pragma unroll
  for (int t = 0; t < 4; ++t) acc[t] = (f32x4){0.f, 0.f, 0.f, 0.f};

  nf4_gemm_pipe(crow, srow, arow, 16 * MDIM, nkb, lut, q * 8, acc);

  float* op = part + (size_t)sp * (TOKN * HD);
#pragma unroll
  for (int t = 0; t < 4; ++t)
#pragma unroll
    for (int rr = 0; rr < 4; ++rr) {
      int token = t * 16 + 4 * q + rr;
      op[(size_t)token * HD + nbase + r15] = acc[t][rr];
    }
}

__global__ void k_reduce_out(const float* __restrict__ part,
                             float* __restrict__ out, int dsplit) {
  int i = blockIdx.x * blockDim.x + threadIdx.x;
  float4 a = ((const float4*)part)[i];
  for (int s = 1; s < dsplit; ++s) {
    float4 b = ((const float4*)(part + (size_t)s * (TOKN * HD)))[i];
    a.x += b.x; a.y += b.y; a.z += b.z; a.w += b.w;
  }
  ((float4*)out)[i] = a;
}

extern "C" void kernel_launch(void* const* d_in, const int* in_sizes, int n_in,
                              void* d_out, int out_size, void* d_ws, size_t ws_size,
                              hipStream_t stream) {
  (void)in_sizes; (void)n_in; (void)out_size;
  const float* x  = (const float*)d_in[0];
  const int*   gc = (const int*)d_in[1];
  const float* gs = (const float*)d_in[2];
  const int*   uc = (const int*)d_in[3];
  const float* us = (const float*)d_in[4];
  const int*   dc = (const int*)d_in[5];
  const float* ds = (const float*)d_in[6];
  float* out = (float*)d_out;

  const size_t XH_B   = (size_t)TOKN * HD * sizeof(_Float16);    // 512 KB
  const size_t H_B    = (size_t)TOKN * MDIM * sizeof(_Float16);  // 1.75 MB
  const size_t GU1_B  = (size_t)TOKN * MDIM * sizeof(float);     // 3.5 MB per split per mat
  const size_t D1_B   = (size_t)TOKN * HD * sizeof(float);       // 1.0 MB per split
  const size_t FIX_B  = XH_B + H_B;

  // workspace tiers: pick largest split config that fits (ws >= 12.7MB known-safe)
  int gsplit, dsplit;
  size_t avail = (ws_size > FIX_B) ? ws_size - FIX_B : 0;
  if (avail >= 8 * GU1_B) { gsplit = 4; dsplit = 16; }        // needs 30.3 MB total
  else if (avail >= 4 * GU1_B) { gsplit = 2; dsplit = 14; }   // needs 17.1 MB total
  else { gsplit = 1; dsplit = 8; }                            // needs 10.7 MB total

  char* w = (char*)d_ws;
  _Float16* xh    = (_Float16*)w;
  _Float16* hbuf  = (_Float16*)(w + XH_B);
  float*    gpart = (float*)(w + FIX_B);
  float*    upart = (float*)(w + FIX_B + (size_t)gsplit * GU1_B);
  float*    dpart = (float*)(w + FIX_B);   // overlays g/u parts (dead by then)
  (void)D1_B;

  k_cvt_x        <<<256, 256, 0, stream>>>(x, xh);
  k_gemm_gu      <<<448 * gsplit, 256, 0, stream>>>(gc, gs, uc, us, xh, gpart, upart, gsplit);
  k_reduce_swiglu<<<896, 256, 0, stream>>>(gpart, upart, hbuf, gsplit);
  k_gemm_down    <<<64 * dsplit, 256, 0, stream>>>(dc, ds, hbuf, dpart, dsplit);
  k_reduce_out   <<<256, 256, 0, stream>>>(dpart, out, dsplit);
}

// Round 3
// 646.942 us; speedup vs baseline: 1.1491x; 1.0990x over previous
//
#include <hip/hip_runtime.h>
#include <hip/hip_fp16.h>
#include <stdint.h>

#define HD   4096
#define MDIM 14336
#define TOKN 64

typedef _Float16 half8 __attribute__((ext_vector_type(8)));
typedef float    f32x4 __attribute__((ext_vector_type(4)));

// LDS layout (bytes):
//   B codes dbuf  [2][64 rows][256 B]  = 32768
//   A fp16  dbuf  [2][64 tok ][128 B]  = 16384
//   pair-LUT 256*4                     = 1024
#define B_OFF   0
#define A_OFF   32768
#define LUT_OFF 49152
#define LDS_BYTES 50176

__constant__ float NF4_TBL[16] = {
    -1.0f, -0.6961928009986877f, -0.5250730514526367f, -0.39491748809814453f,
    -0.28444138169288635f, -0.18477343022823334f, -0.09105003625154495f, 0.0f,
    0.07958029955625534f, 0.16093020141124725f, 0.24611230194568634f,
    0.33791524171829224f, 0.44070982933044434f, 0.5626170039176941f,
    0.8333333134651184f, 1.0f};

__device__ __forceinline__ void gload_lds16(const void* g, void* l) {
  __builtin_amdgcn_global_load_lds(
      (const __attribute__((address_space(1))) void*)g,
      (__attribute__((address_space(3))) void*)l, 16, 0, 0);
}

__device__ __forceinline__ void lut_fill(uint32_t* lut, int tid) {
  if (tid < 256) {
    __half lo = __float2half(NF4_TBL[tid & 15]);
    __half hi = __float2half(NF4_TBL[tid >> 4]);
    lut[tid] = (uint32_t)__half_as_ushort(lo) |
               ((uint32_t)__half_as_ushort(hi) << 16);
  }
}

__device__ __forceinline__ half8 mk_bfrag(const uint32_t* lut, int4 ca, int4 cb) {
  union { uint32_t u[4]; half8 h; } bu;
  bu.u[0] = lut[ca.x | (ca.y << 4)];
  bu.u[1] = lut[ca.z | (ca.w << 4)];
  bu.u[2] = lut[cb.x | (cb.y << 4)];
  bu.u[3] = lut[cb.z | (cb.w << 4)];
  return bu.h;
}

// stage 64x64 int32 code tile (16KB): 4 issues x 256 thr x 16B, row-XOR-swizzled source
__device__ __forceinline__ void stage_codes(char* lds, int buf, const char* cbase,
                                            size_t crow_bytes, int tid) {
  int lane = tid & 63, wid = tid >> 6;
  char* dstw = lds + B_OFF + buf * 16384 + wid * 1024;
  int rb = wid * 4 + (lane >> 4);
  int b  = (lane & 15) * 16;
#pragma unroll
  for (int j = 0; j < 4; ++j) {
    int row = j * 16 + rb;
    gload_lds16(cbase + (size_t)row * crow_bytes + (b ^ ((row & 7) << 4)),
                dstw + j * 4096);
  }
}

// stage 64x64 fp16 A tile (8KB): 2 issues x 256 thr x 16B, row-XOR-swizzled source
__device__ __forceinline__ void stage_a(char* lds, int buf, const char* abase,
                                        size_t arow_bytes, int tid) {
  int lane = tid & 63, wid = tid >> 6;
  char* dstw = lds + A_OFF + buf * 8192 + wid * 1024;
  int tb = wid * 8 + (lane >> 3);
  int b  = (lane & 7) * 16;
#pragma unroll
  for (int j = 0; j < 2; ++j) {
    int tok = j * 32 + tb;
    gload_lds16(abase + (size_t)tok * arow_bytes + (b ^ ((tok & 7) << 4)),
                dstw + j * 4096);
  }
}

// one 64-code K-step from LDS buffers: 4 B-b128 + 8 A-b128 + 8 lut + 8 MFMA per wave
__device__ __forceinline__ void compute_step(const char* lds, int buf,
                                             const uint32_t* lut, float scale,
                                             int wid, int r15, int q, f32x4 acc[4]) {
  const char* Bb = lds + B_OFF + buf * 16384;
  const char* Ab = lds + A_OFF + buf * 8192;
  int swz = (r15 & 7) << 4;
  int brow = (wid * 16 + r15) * 256;
  _Float16 sh = (_Float16)scale;
  half8 sv = {sh, sh, sh, sh, sh, sh, sh, sh};
#pragma unroll
  for (int kk = 0; kk < 2; ++kk) {
    int4 ca = *(const int4*)(Bb + brow + ((kk * 128 + q * 32) ^ swz));
    int4 cb = *(const int4*)(Bb + brow + ((kk * 128 + q * 32 + 16) ^ swz));
    half8 bf = mk_bfrag(lut, ca, cb) * sv;
#pragma unroll
    for (int t = 0; t < 4; ++t) {
      half8 af = *(const half8*)(Ab + (t * 16 + r15) * 128 + ((kk * 64 + q * 16) ^ swz));
      acc[t] = __builtin_amdgcn_mfma_f32_16x16x32_f16(af, bf, acc[t], 0, 0, 0);
    }
  }
}

// x fp32 -> fp16
__global__ void k_cvt_x(const float* __restrict__ x, _Float16* __restrict__ xh) {
  int i = blockIdx.x * blockDim.x + threadIdx.x;
  float4 v = ((const float4*)x)[i];
  union { _Float16 h[4]; uint2 u; } o;
  o.h[0] = (_Float16)v.x; o.h[1] = (_Float16)v.y;
  o.h[2] = (_Float16)v.z; o.h[3] = (_Float16)v.w;
  ((uint2*)xh)[i] = o.u;
}

// gate & up GEMM: grid = 448*gsplit; block covers 64 out-cols x 64 tokens
__global__ __launch_bounds__(256, 3) void k_gemm_gu(
    const int* __restrict__ gc, const float* __restrict__ gs,
    const int* __restrict__ uc, const float* __restrict__ us,
    const _Float16* __restrict__ xh,
    float* __restrict__ gpart, float* __restrict__ upart, int gsplit)
{
  __shared__ char lds[LDS_BYTES];
  uint32_t* lut = (uint32_t*)(lds + LUT_OFF);
  int tid = threadIdx.x;
  lut_fill(lut, tid);

  int bx = blockIdx.x;
  int sp = bx % gsplit;
  int r  = bx / gsplit;
  int mat  = (r >= 224);
  int mblk = mat ? r - 224 : r;
  const int*   codes = mat ? uc : gc;
  const float* scl   = mat ? us : gs;
  float*       outp  = (mat ? upart : gpart) + (size_t)sp * (TOKN * MDIM);

  int kch = HD / gsplit;
  int nt  = kch / 64;

  int lane = tid & 63, wid = tid >> 6;
  int r15 = lane & 15, q = lane >> 4;
  int mbase = mblk * 64;

  const char* cblk = (const char*)(codes + (size_t)mbase * HD + (size_t)sp * kch);
  const char* ablk = (const char*)(xh + (size_t)sp * kch);
  const float* srow = scl + (size_t)(mbase + wid * 16 + r15) * (HD / 64) + (size_t)sp * nt;

  f32x4 acc[4];
#pragma unroll
  for (int t = 0; t < 4; ++t) acc[t] = (f32x4){0.f, 0.f, 0.f, 0.f};

  float sc_cur = srow[0];
  stage_codes(lds, 0, cblk, (size_t)HD * 4, tid);
  stage_a(lds, 0, ablk, (size_t)HD * 2, tid);
  __syncthreads();

  int cur = 0;
  for (int t = 0; t < nt; ++t) {
    float sc_nxt = sc_cur;
    if (t + 1 < nt) {
      sc_nxt = srow[t + 1];
      stage_codes(lds, cur ^ 1, cblk + (size_t)(t + 1) * 256, (size_t)HD * 4, tid);
      stage_a(lds, cur ^ 1, ablk + (size_t)(t + 1) * 128, (size_t)HD * 2, tid);
    }
    compute_step(lds, cur, lut, sc_cur, wid, r15, q, acc);
    __syncthreads();
    cur ^= 1;
    sc_cur = sc_nxt;
  }

#pragma unroll
  for (int t = 0; t < 4; ++t)
#pragma unroll
    for (int rr = 0; rr < 4; ++rr) {
      int token = t * 16 + 4 * q + rr;
      outp[(size_t)token * MDIM + mbase + wid * 16 + r15] = acc[t][rr];
    }
}

// fused split-reduce + SwiGLU, fp32 parts -> fp16 h
__global__ void k_reduce_swiglu(const float* __restrict__ gpart,
                                const float* __restrict__ upart,
                                _Float16* __restrict__ h, int gsplit) {
  int i = blockIdx.x * blockDim.x + threadIdx.x;
  float4 g = ((const float4*)gpart)[i];
  float4 u = ((const float4*)upart)[i];
  for (int s = 1; s < gsplit; ++s) {
    float4 gb = ((const float4*)(gpart + (size_t)s * (TOKN * MDIM)))[i];
    float4 ub = ((const float4*)(upart + (size_t)s * (TOKN * MDIM)))[i];
    g.x += gb.x; g.y += gb.y; g.z += gb.z; g.w += gb.w;
    u.x += ub.x; u.y += ub.y; u.z += ub.z; u.w += ub.w;
  }
  union { _Float16 h4[4]; uint2 w; } o;
  o.h4[0] = (_Float16)(g.x / (1.f + __expf(-g.x)) * u.x);
  o.h4[1] = (_Float16)(g.y / (1.f + __expf(-g.y)) * u.y);
  o.h4[2] = (_Float16)(g.z / (1.f + __expf(-g.z)) * u.z);
  o.h4[3] = (_Float16)(g.w / (1.f + __expf(-g.w)) * u.w);
  ((uint2*)h)[i] = o.w;
}

// down-proj GEMM: grid = 64*dsplit
__global__ __launch_bounds__(256, 3) void k_gemm_down(
    const int* __restrict__ dc, const float* __restrict__ ds,
    const _Float16* __restrict__ h, float* __restrict__ part, int dsplit)
{
  __shared__ char lds[LDS_BYTES];
  uint32_t* lut = (uint32_t*)(lds + LUT_OFF);
  int tid = threadIdx.x;
  lut_fill(lut, tid);

  int bx = blockIdx.x;
  int sp   = bx % dsplit;
  int nblk = bx / dsplit;

  int kch = MDIM / dsplit;
  int nt  = kch / 64;

  int lane = tid & 63, wid = tid >> 6;
  int r15 = lane & 15, q = lane >> 4;
  int nbase = nblk * 64;

  const char* cblk = (const char*)(dc + (size_t)nbase * MDIM + (size_t)sp * kch);
  const char* ablk = (const char*)(h + (size_t)sp * kch);
  const float* srow = ds + (size_t)(nbase + wid * 16 + r15) * (MDIM / 64) + (size_t)sp * nt;

  f32x4 acc[4];
#pragma unroll
  for (int t = 0; t < 4; ++t) acc[t] = (f32x4){0.f, 0.f, 0.f, 0.f};

  float sc_cur = srow[0];
  stage_codes(lds, 0, cblk, (size_t)MDIM * 4, tid);
  stage_a(lds, 0, ablk, (size_t)MDIM * 2, tid);
  __syncthreads();

  int cur = 0;
  for (int t = 0; t < nt; ++t) {
    float sc_nxt = sc_cur;
    if (t + 1 < nt) {
      sc_nxt = srow[t + 1];
      stage_codes(lds, cur ^ 1, cblk + (size_t)(t + 1) * 256, (size_t)MDIM * 4, tid);
      stage_a(lds, cur ^ 1, ablk + (size_t)(t + 1) * 128, (size_t)MDIM * 2, tid);
    }
    compute_step(lds, cur, lut, sc_cur, wid, r15, q, acc);
    __syncthreads();
    cur ^= 1;
    sc_cur = sc_nxt;
  }

  float* op = part + (size_t)sp * (TOKN * HD);
#pragma unroll
  for (int t = 0; t < 4; ++t)
#pragma unroll
    for (int rr = 0; rr < 4; ++rr) {
      int token = t * 16 + 4 * q + rr;
      op[(size_t)token * HD + nbase + wid * 16 + r15] = acc[t][rr];
    }
}

__global__ void k_reduce_out(const float* __restrict__ part,
                             float* __restrict__ out, int dsplit) {
  int i = blockIdx.x * blockDim.x + threadIdx.x;
  float4 a = ((const float4*)part)[i];
  for (int s = 1; s < dsplit; ++s) {
    float4 b = ((const float4*)(part + (size_t)s * (TOKN * HD)))[i];
    a.x += b.x; a.y += b.y; a.z += b.z; a.w += b.w;
  }
  ((float4*)out)[i] = a;
}

extern "C" void kernel_launch(void* const* d_in, const int* in_sizes, int n_in,
                              void* d_out, int out_size, void* d_ws, size_t ws_size,
                              hipStream_t stream) {
  (void)in_sizes; (void)n_in; (void)out_size;
  const float* x  = (const float*)d_in[0];
  const int*   gc = (const int*)d_in[1];
  const float* gs = (const float*)d_in[2];
  const int*   uc = (const int*)d_in[3];
  const float* us = (const float*)d_in[4];
  const int*   dc = (const int*)d_in[5];
  const float* ds = (const float*)d_in[6];
  float* out = (float*)d_out;

  const size_t XH_B  = (size_t)TOKN * HD * sizeof(_Float16);    // 512 KB
  const size_t H_B   = (size_t)TOKN * MDIM * sizeof(_Float16);  // 1.75 MB
  const size_t GU1_B = (size_t)TOKN * MDIM * sizeof(float);     // 3.5 MB per split per mat
  const size_t FIX_B = XH_B + H_B;

  int gsplit, dsplit;
  size_t avail = (ws_size > FIX_B) ? ws_size - FIX_B : 0;
  if (avail >= 4 * GU1_B) { gsplit = 2; dsplit = 8; }   // 16.3 MB total (ws >= 30MB observed)
  else { gsplit = 1; dsplit = 4; }                      // 9.25 MB total

  char* w = (char*)d_ws;
  _Float16* xh    = (_Float16*)w;
  _Float16* hbuf  = (_Float16*)(w + XH_B);
  float*    gpart = (float*)(w + FIX_B);
  float*    upart = (float*)(w + FIX_B + (size_t)gsplit * GU1_B);
  float*    dpart = (float*)(w + FIX_B);   // overlays g/u parts (dead by then)

  k_cvt_x        <<<256, 256, 0, stream>>>(x, xh);
  k_gemm_gu      <<<448 * gsplit, 256, 0, stream>>>(gc, gs, uc, us, xh, gpart, upart, gsplit);
  k_reduce_swiglu<<<896, 256, 0, stream>>>(gpart, upart, hbuf, gsplit);
  k_gemm_down    <<<64 * dsplit, 256, 0, stream>>>(dc, ds, hbuf, dpart, dsplit);
  k_reduce_out   <<<256, 256, 0, stream>>>(dpart, out, dsplit);
}

// Round 5
// 625.610 us; speedup vs baseline: 1.1883x; 1.0341x over previous
//
#include <hip/hip_runtime.h>
#include <hip/hip_fp16.h>
#include <stdint.h>

#define HD   4096
#define MDIM 14336
#define TOKN 64

typedef _Float16 half8 __attribute__((ext_vector_type(8)));
typedef float    f32x4 __attribute__((ext_vector_type(4)));

// LDS layout (bytes):
//   B codes 3-buf [3][64 rows][256 B] = 49152 @ 0
//   A fp16  3-buf [3][64 tok ][128 B] = 24576 @ 49152
//   pair-LUT 256*4                    =  1024 @ 73728
//   scales f16 [nt<=32][64]           =  4096 @ 74752
#define B_OFF   0
#define A_OFF   49152
#define LUT_OFF 73728
#define SC_OFF  74752
#define LDS_BYTES 78848   /* 77 KB -> 2 blocks/CU */

__constant__ float NF4_TBL[16] = {
    -1.0f, -0.6961928009986877f, -0.5250730514526367f, -0.39491748809814453f,
    -0.28444138169288635f, -0.18477343022823334f, -0.09105003625154495f, 0.0f,
    0.07958029955625534f, 0.16093020141124725f, 0.24611230194568634f,
    0.33791524171829224f, 0.44070982933044434f, 0.5626170039176941f,
    0.8333333134651184f, 1.0f};

__device__ __forceinline__ void gload_lds16(const void* g, void* l) {
  __builtin_amdgcn_global_load_lds(
      (const __attribute__((address_space(1))) void*)g,
      (__attribute__((address_space(3))) void*)l, 16, 0, 0);
}

__device__ __forceinline__ void lut_fill(uint32_t* lut, int tid) {
  if (tid < 256) {
    __half lo = __float2half(NF4_TBL[tid & 15]);
    __half hi = __float2half(NF4_TBL[tid >> 4]);
    lut[tid] = (uint32_t)__half_as_ushort(lo) |
               ((uint32_t)__half_as_ushort(hi) << 16);
  }
}

__device__ __forceinline__ half8 mk_bfrag(const uint32_t* lut, int4 ca, int4 cb) {
  union { uint32_t u[4]; half8 h; } bu;
  bu.u[0] = lut[ca.x | (ca.y << 4)];
  bu.u[1] = lut[ca.z | (ca.w << 4)];
  bu.u[2] = lut[cb.x | (cb.y << 4)];
  bu.u[3] = lut[cb.z | (cb.w << 4)];
  return bu.h;
}

// stage 64x64 int32 code tile (16KB) into bufbase: 4 issues/thread, XOR-swizzled source
__device__ __forceinline__ void stage_codes(char* bufbase, const char* cbase,
                                            size_t crow_bytes, int tid) {
  int lane = tid & 63, wid = tid >> 6;
  char* dstw = bufbase + wid * 1024;
  int rb = wid * 4 + (lane >> 4);
  int b  = (lane & 15) * 16;
#pragma unroll
  for (int j = 0; j < 4; ++j) {
    int row = j * 16 + rb;
    gload_lds16(cbase + (size_t)row * crow_bytes + (b ^ ((row & 7) << 4)),
                dstw + j * 4096);
  }
}

// stage 64x64 fp16 A tile (8KB) into bufbase: 2 issues/thread, XOR-swizzled source
__device__ __forceinline__ void stage_a(char* bufbase, const char* abase,
                                        size_t arow_bytes, int tid) {
  int lane = tid & 63, wid = tid >> 6;
  char* dstw = bufbase + wid * 1024;
  int tb = wid * 8 + (lane >> 3);
  int b  = (lane & 7) * 16;
#pragma unroll
  for (int j = 0; j < 2; ++j) {
    int tok = j * 32 + tb;
    gload_lds16(abase + (size_t)tok * arow_bytes + (b ^ ((tok & 7) << 4)),
                dstw + j * 4096);
  }
}

// 6 VMEM issues per wave per step — vmcnt accounting relies on this
__device__ __forceinline__ void stage_step(char* lds, int b,
                                           const char* cptr, size_t crow_bytes,
                                           const char* aptr, size_t arow_bytes, int tid) {
  stage_codes(lds + B_OFF + b * 16384, cptr, crow_bytes, tid);
  stage_a(lds + A_OFF + b * 8192, aptr, arow_bytes, tid);
}

// one 64-code K-step from LDS buffer b: 4 B-b128 + 8 A-b128 + 8 lut + 8 MFMA per wave
__device__ __forceinline__ void compute_step(const char* lds, int b,
                                             const uint32_t* lut, _Float16 sh,
                                             int wid, int r15, int q, f32x4 acc[4]) {
  const char* Bb = lds + B_OFF + b * 16384;
  const char* Ab = lds + A_OFF + b * 8192;
  int swz = (r15 & 7) << 4;
  int brow = (wid * 16 + r15) * 256;
  half8 sv = {sh, sh, sh, sh, sh, sh, sh, sh};
#pragma unroll
  for (int kk = 0; kk < 2; ++kk) {
    int4 ca = *(const int4*)(Bb + brow + ((kk * 128 + q * 32) ^ swz));
    int4 cb = *(const int4*)(Bb + brow + ((kk * 128 + q * 32 + 16) ^ swz));
    half8 bf = mk_bfrag(lut, ca, cb) * sv;
#pragma unroll
    for (int t = 0; t < 4; ++t) {
      half8 af = *(const half8*)(Ab + (t * 16 + r15) * 128 + ((kk * 64 + q * 16) ^ swz));
      acc[t] = __builtin_amdgcn_mfma_f32_16x16x32_f16(af, bf, acc[t], 0, 0, 0);
    }
  }
}

// Counted-vmcnt 3-buffer pipelined K-loop. nt <= 32, nt >= 3.
__device__ __forceinline__ void nf4_gemm_core(
    const char* __restrict__ cblk, size_t crow_bytes,
    const char* __restrict__ ablk, size_t arow_bytes,
    const float* __restrict__ sgbase, int sstride,
    int nt, char* lds, int tid, f32x4 acc[4])
{
  uint32_t* lut = (uint32_t*)(lds + LUT_OFF);
  _Float16* scl_l = (_Float16*)(lds + SC_OFF);
  lut_fill(lut, tid);
  // pre-stage all scales as f16, layout [t][row] (broadcast across q at read)
  for (int i = tid; i < 64 * nt; i += 256) {
    int t = i >> 6, row = i & 63;
    scl_l[i] = (_Float16)sgbase[(size_t)row * sstride + t];
  }
  __syncthreads();   // drains vmcnt to 0: clean baseline for counted waits

  int lane = tid & 63, wid = tid >> 6;
  int r15 = lane & 15, q = lane >> 4;
  int rowid = wid * 16 + r15;

  stage_step(lds, 0, cblk,       crow_bytes, ablk,       arow_bytes, tid);
  stage_step(lds, 1, cblk + 256, crow_bytes, ablk + 128, arow_bytes, tid);
  stage_step(lds, 2, cblk + 512, crow_bytes, ablk + 256, arow_bytes, tid);

  int b = 0;
  for (int t = 0; t < nt; ++t) {
    if (t < nt - 2)       asm volatile("s_waitcnt vmcnt(12)" ::: "memory");
    else if (t == nt - 2) asm volatile("s_waitcnt vmcnt(6)" ::: "memory");
    else                  asm volatile("s_waitcnt vmcnt(0)" ::: "memory");
    __builtin_amdgcn_s_barrier();
    _Float16 sh = scl_l[t * 64 + rowid];
    compute_step(lds, b, lut, sh, wid, r15, q, acc);
    __builtin_amdgcn_s_barrier();        // all waves done reading buf b
    if (t < nt - 3)                      // (t+3)%3 == b: overwrite just-freed buf
      stage_step(lds, b, cblk + (size_t)(t + 3) * 256, crow_bytes,
                 ablk + (size_t)(t + 3) * 128, arow_bytes, tid);
    b = (b == 2) ? 0 : b + 1;
  }
}

// x fp32 -> fp16
__global__ void k_cvt_x(const float* __restrict__ x, _Float16* __restrict__ xh) {
  int i = blockIdx.x * blockDim.x + threadIdx.x;
  float4 v = ((const float4*)x)[i];
  union { _Float16 h[4]; uint2 u; } o;
  o.h[0] = (_Float16)v.x; o.h[1] = (_Float16)v.y;
  o.h[2] = (_Float16)v.z; o.h[3] = (_Float16)v.w;
  ((uint2*)xh)[i] = o.u;
}

// gate & up GEMM: grid = 448*gsplit; block = 64 out-cols x 64 tokens
__global__ __launch_bounds__(256, 2) void k_gemm_gu(
    const int* __restrict__ gc, const float* __restrict__ gs,
    const int* __restrict__ uc, const float* __restrict__ us,
    const _Float16* __restrict__ xh,
    float* __restrict__ gpart, float* __restrict__ upart, int gsplit)
{
  __shared__ char lds[LDS_BYTES];
  int tid = threadIdx.x;
  int bx = blockIdx.x;
  int sp = bx % gsplit;
  int r  = bx / gsplit;
  int mat  = (r >= 224);
  int mblk = mat ? r - 224 : r;
  const int*   codes = mat ? uc : gc;
  const float* scl   = mat ? us : gs;
  float*       outp  = (mat ? upart : gpart) + (size_t)sp * (TOKN * MDIM);

  int kch = HD / gsplit;
  int nt  = kch / 64;
  int mbase = mblk * 64;

  const char* cblk = (const char*)(codes + (size_t)mbase * HD + (size_t)sp * kch);
  const char* ablk = (const char*)(xh + (size_t)sp * kch);
  const float* sgbase = scl + (size_t)mbase * (HD / 64) + (size_t)sp * nt;

  f32x4 acc[4];
#pragma unroll
  for (int t = 0; t < 4; ++t) acc[t] = (f32x4){0.f, 0.f, 0.f, 0.f};

  nf4_gemm_core(cblk, (size_t)HD * 4, ablk, (size_t)HD * 2,
                sgbase, HD / 64, nt, lds, tid, acc);

  int lane = tid & 63, wid = tid >> 6;
  int r15 = lane & 15, q = lane >> 4;
#pragma unroll
  for (int t = 0; t < 4; ++t)
#pragma unroll
    for (int rr = 0; rr < 4; ++rr) {
      int token = t * 16 + 4 * q + rr;
      outp[(size_t)token * MDIM + mbase + wid * 16 + r15] = acc[t][rr];
    }
}

// fused split-reduce + SwiGLU, fp32 parts -> fp16 h
__global__ void k_reduce_swiglu(const float* __restrict__ gpart,
                                const float* __restrict__ upart,
                                _Float16* __restrict__ h, int gsplit) {
  int i = blockIdx.x * blockDim.x + threadIdx.x;
  float4 g = ((const float4*)gpart)[i];
  float4 u = ((const float4*)upart)[i];
  for (int s = 1; s < gsplit; ++s) {
    float4 gb = ((const float4*)(gpart + (size_t)s * (TOKN * MDIM)))[i];
    float4 ub = ((const float4*)(upart + (size_t)s * (TOKN * MDIM)))[i];
    g.x += gb.x; g.y += gb.y; g.z += gb.z; g.w += gb.w;
    u.x += ub.x; u.y += ub.y; u.z += ub.z; u.w += ub.w;
  }
  union { _Float16 h4[4]; uint2 w; } o;
  o.h4[0] = (_Float16)(g.x / (1.f + __expf(-g.x)) * u.x);
  o.h4[1] = (_Float16)(g.y / (1.f + __expf(-g.y)) * u.y);
  o.h4[2] = (_Float16)(g.z / (1.f + __expf(-g.z)) * u.z);
  o.h4[3] = (_Float16)(g.w / (1.f + __expf(-g.w)) * u.w);
  ((uint2*)h)[i] = o.w;
}

// down-proj GEMM: grid = 64*dsplit
__global__ __launch_bounds__(256, 2) void k_gemm_down(
    const int* __restrict__ dc, const float* __restrict__ ds,
    const _Float16* __restrict__ h, float* __restrict__ part, int dsplit)
{
  __shared__ char lds[LDS_BYTES];
  int tid = threadIdx.x;
  int bx = blockIdx.x;
  int sp   = bx % dsplit;
  int nblk = bx / dsplit;

  int kch = MDIM / dsplit;
  int nt  = kch / 64;
  int nbase = nblk * 64;

  const char* cblk = (const char*)(dc + (size_t)nbase * MDIM + (size_t)sp * kch);
  const char* ablk = (const char*)(h + (size_t)sp * kch);
  const float* sgbase = ds + (size_t)nbase * (MDIM / 64) + (size_t)sp * nt;

  f32x4 acc[4];
#pragma unroll
  for (int t = 0; t < 4; ++t) acc[t] = (f32x4){0.f, 0.f, 0.f, 0.f};

  nf4_gemm_core(cblk, (size_t)MDIM * 4, ablk, (size_t)MDIM * 2,
                sgbase, MDIM / 64, nt, lds, tid, acc);

  int lane = tid & 63, wid = tid >> 6;
  int r15 = lane & 15, q = lane >> 4;
  float* op = part + (size_t)sp * (TOKN * HD);
#pragma unroll
  for (int t = 0; t < 4; ++t)
#pragma unroll
    for (int rr = 0; rr < 4; ++rr) {
      int token = t * 16 + 4 * q + rr;
      op[(size_t)token * HD + nbase + wid * 16 + r15] = acc[t][rr];
    }
}

__global__ void k_reduce_out(const float* __restrict__ part,
                             float* __restrict__ out, int dsplit) {
  int i = blockIdx.x * blockDim.x + threadIdx.x;
  float4 a = ((const float4*)part)[i];
  for (int s = 1; s < dsplit; ++s) {
    float4 b = ((const float4*)(part + (size_t)s * (TOKN * HD)))[i];
    a.x += b.x; a.y += b.y; a.z += b.z; a.w += b.w;
  }
  ((float4*)out)[i] = a;
}

extern "C" void kernel_launch(void* const* d_in, const int* in_sizes, int n_in,
                              void* d_out, int out_size, void* d_ws, size_t ws_size,
                              hipStream_t stream) {
  (void)in_sizes; (void)n_in; (void)out_size; (void)ws_size;
  const float* x  = (const float*)d_in[0];
  const int*   gc = (const int*)d_in[1];
  const float* gs = (const float*)d_in[2];
  const int*   uc = (const int*)d_in[3];
  const float* us = (const float*)d_in[4];
  const int*   dc = (const int*)d_in[5];
  const float* ds = (const float*)d_in[6];
  float* out = (float*)d_out;

  const size_t XH_B  = (size_t)TOKN * HD * sizeof(_Float16);    // 512 KB
  const size_t H_B   = (size_t)TOKN * MDIM * sizeof(_Float16);  // 1.75 MB
  const size_t GU1_B = (size_t)TOKN * MDIM * sizeof(float);     // 3.5 MB per split per mat
  const size_t FIX_B = XH_B + H_B;

  // nt must be <= 32 for the LDS scale buffer: gsplit>=2, dsplit>=8
  const int gsplit = 2, dsplit = 8;   // 16.3 MB total; ws >= 30 MB observed

  char* w = (char*)d_ws;
  _Float16* xh    = (_Float16*)w;
  _Float16* hbuf  = (_Float16*)(w + XH_B);
  float*    gpart = (float*)(w + FIX_B);
  float*    upart = (float*)(w + FIX_B + (size_t)gsplit * GU1_B);
  float*    dpart = (float*)(w + FIX_B);   // overlays g/u parts (dead by then)

  k_cvt_x        <<<256, 256, 0, stream>>>(x, xh);
  k_gemm_gu      <<<448 * gsplit, 256, 0, stream>>>(gc, gs, uc, us, xh, gpart, upart, gsplit);
  k_reduce_swiglu<<<896, 256, 0, stream>>>(gpart, upart, hbuf, gsplit);
  k_gemm_down    <<<64 * dsplit, 256, 0, stream>>>(dc, ds, hbuf, dpart, dsplit);
  k_reduce_out   <<<256, 256, 0, stream>>>(dpart, out, dsplit);
}